// Round 7
// baseline (374.938 us; speedup 1.0000x reference)
//
#include <hip/hip_runtime.h>
#include <cstdint>

typedef __bf16          bf16x8 __attribute__((ext_vector_type(8)));
typedef float           f32x4  __attribute__((ext_vector_type(4)));
typedef unsigned short  u16x8  __attribute__((ext_vector_type(8)));
typedef unsigned int    u32x4  __attribute__((ext_vector_type(4)));

#define MFMA16(a,b,c) __builtin_amdgcn_mfma_f32_16x16x32_bf16((a),(b),(c),0,0,0)

__device__ __forceinline__ float rcpf(float x) { return __builtin_amdgcn_rcpf(x); }
__device__ __forceinline__ float ex2(float x)  { return __builtin_amdgcn_exp2f(x); }

// truncation hi/lo split: hi = top16(v), lo = trunc16(v - hi).
__device__ __forceinline__ void split2(float v, unsigned short& hi, unsigned short& lo) {
    unsigned u = __builtin_bit_cast(unsigned, v);
    hi = (unsigned short)(u >> 16);
    float rem = v - __builtin_bit_cast(float, u & 0xffff0000u);
    lo = (unsigned short)(__builtin_bit_cast(unsigned, rem) >> 16);
}
__device__ __forceinline__ __bf16 bfbits(unsigned short b) { return __builtin_bit_cast(__bf16, b); }

// one v_perm_b32: result = hi16(b)<<16 | hi16(a)   (pair-pack of truncated bf16)
__device__ __forceinline__ unsigned packhi2(float a, float b) {
    return __builtin_amdgcn_perm(__builtin_bit_cast(unsigned, b),
                                 __builtin_bit_cast(unsigned, a), 0x07060302u);
}
__device__ __forceinline__ float truncrem(float v) {
    return v - __builtin_bit_cast(float, __builtin_bit_cast(unsigned, v) & 0xffff0000u);
}

// ---------------------------------------------------------------------------
// R10 = R9 (174 µs: 2 fat waves, folded gate scales) with BARRIERS HALVED:
// pipeline deepened so all cross-role data has 2 steps of slack -> 1 barrier
// per 2 steps (52 total vs 102). R9 post-mortem: busy-floor ~118 µs reached;
// idle ~1300 cyc/step concentrated at barriers (4 waves/SIMD is grid-capped
// at 2048 blocks, can't raise).
//   slots: xh[4], h0[4] ring-buffered by step mod 4 (compile-time in the
//   4-step unrolled body); role1's cell1 lags 2 steps, proj leads 2 steps;
//   x prefetch in 4 named register buffers (load at interval s, consume s+1).
// Hazards: every cross-wave RAW/WAR is slot-disjoint within an interval and
// crosses exactly one barrier (walked for xh, h0, h1; h1/cst role-private).
// Roles: role0 = cell0(2s),cell0(2s+1).  role1 = cell1(2s-2),cell1(2s-1) +
// proj(2s+2),proj(2s+3) + loadx(2s+4),(2s+5).
// Staging images [plane hi/lo][m*24 + k]; pos 13 of every row = 1.0 (hi) so
// weight row k=13 (bias; +FORGET_BIAS on f, then scaled) supplies the bias;
// rows 14/15 zero. h/xh writes col<13-masked to preserve pos 13.
// ---------------------------------------------------------------------------

constexpr float SN1 = -1.4426950408889634f;   // -log2(e)
constexpr float SN2 = -2.8853900817779268f;   // -2 log2(e)
constexpr float C2  =  2.8853900817779268f;   //  2 log2(e)

__global__ __launch_bounds__(128, 4)
void lstm_fused(const float* __restrict__ x,
                const float* __restrict__ w_hidden,
                const float* __restrict__ b_hidden,
                const float* __restrict__ k0,
                const float* __restrict__ b0,
                const float* __restrict__ k1,
                const float* __restrict__ b1,
                const float* __restrict__ w_out,
                const float* __restrict__ b_out,
                float* __restrict__ out)
{
    __shared__ __attribute__((aligned(16))) unsigned short xh_s[4][2][384];
    __shared__ __attribute__((aligned(16))) unsigned short h0_s[4][2][384];
    __shared__ __attribute__((aligned(16))) unsigned short h1_s[2][384];

    const int lane = threadIdx.x & 63;
    const int role = threadIdx.x >> 6;
    const int col  = lane & 15;
    const int q    = lane >> 4;
    const int qh   = q & 1;
    const int s0   = blockIdx.x * 16;

    // ---- init staging: zeros + 1.0 at hi-plane pos 13 of every row ----
    {
        unsigned short* a0 = &xh_s[0][0][0];
        unsigned short* a1 = &h0_s[0][0][0];
        for (int idx = threadIdx.x; idx < 3072; idx += 128) {
            unsigned short v = ((idx % 24) == 13 && ((idx / 384) & 1) == 0)
                             ? (unsigned short)0x3F80 : (unsigned short)0;
            a0[idx] = v; a1[idx] = v;
        }
        unsigned short* a2 = &h1_s[0][0];
        for (int idx = threadIdx.x; idx < 768; idx += 128) {
            unsigned short v = ((idx % 24) == 13 && ((idx / 384) & 1) == 0)
                             ? (unsigned short)0x3F80 : (unsigned short)0;
            a2[idx] = v;
        }
    }

    // ---- role-selected LSTM weights as B-fragments (hi/lo), bias row k=13;
    //      gate pre-scales folded in: g==1 (j) -> SN2, else SN1 ----
    const float* kp = role ? k1 : k0;
    const float* bb = role ? b1 : b0;
    bf16x8 Kh[4], Kl[4];
    #pragma unroll
    for (int g = 0; g < 4; ++g) {
        const float sg = (g == 1) ? SN2 : SN1;
        bf16x8 hv{}, lv{};
        #pragma unroll
        for (int j = 0; j < 8; ++j) {
            int k = 8 * q + j;
            float w = 0.f;
            if (col < 13) {
                if (k < 13)                 w = kp[k * 52 + 13 * g + col];
                else if (k == 13)           w = bb[13 * g + col] + (g == 2 ? 1.f : 0.f); // +FORGET_BIAS on f
                else if (k >= 16 && k < 29) w = kp[(13 + k - 16) * 52 + 13 * g + col];
            }
            w *= sg;
            unsigned short h_, l_;
            split2(w, h_, l_);
            hv[j] = bfbits(h_); lv[j] = bfbits(l_);
        }
        Kh[g] = hv; Kl[g] = lv;
    }

    // ---- proj weights (role 1 only; UNscaled — relu stays explicit) ----
    bf16x8 Ph{}, Pl{};
    if (role) {
        #pragma unroll
        for (int j = 0; j < 8; ++j) {
            int k = 8 * q + j;
            float w = 0.f;
            if (col < 13) {
                if (k < 13)       w = w_hidden[k * 13 + col];
                else if (k == 13) w = b_hidden[col];
            }
            unsigned short h_, l_;
            split2(w, h_, l_);
            Ph[j] = bfbits(h_); Pl[j] = bfbits(l_);
        }
    }

    const float* xrow = x + (size_t)(s0 + col) * 1300;

    // elem with pre-scaled gates: zi,zj,zf,zo arrive as -KL*z (j: -2KL*z);
    // cs is carried as -2KL*c. 5 ex2 + 2 rcp, zero standalone muls on inputs.
    auto elem = [&](float zi, float zj, float zf, float zo, float& cs) -> float {
        float a   = ex2(zi);
        float b   = ex2(zj);
        float fe  = ex2(zf);
        float g   = ex2(zo);
        float opa = 1.f + a, opb = 1.f + b, opf = 1.f + fe;
        float pab = opa * opb;
        float r1  = rcpf(pab * opf);
        float tt  = fmaf(b, C2, -C2);                 // -2KL*(1-b)
        float cn  = fmaf(cs, pab, tt * opf) * r1;     // scaled cell state
        cs = cn;
        float d   = ex2(cn);
        float r2  = rcpf((1.f + d) * (1.f + g));
        return (1.f - d) * r2;                        // tanh(c)*sig(o), unscaled
    };

    auto cell = [&](const unsigned short* inH, const unsigned short* hidH,
                    unsigned short* outH, float* cst) {
        const unsigned short* pA = (q < 2) ? inH : hidH;
        bf16x8 ah = __builtin_bit_cast(bf16x8, *(const u16x8*)(pA + col * 24 + 8 * qh));
        bf16x8 al = __builtin_bit_cast(bf16x8, *(const u16x8*)(pA + 384 + col * 24 + 8 * qh));
        f32x4 z0 = {0.f,0.f,0.f,0.f}, z1 = z0, z2 = z0, z3 = z0;
        z0 = MFMA16(ah, Kh[0], z0); z0 = MFMA16(al, Kh[0], z0); z0 = MFMA16(ah, Kl[0], z0);
        z1 = MFMA16(ah, Kh[1], z1); z1 = MFMA16(al, Kh[1], z1); z1 = MFMA16(ah, Kl[1], z1);
        z2 = MFMA16(ah, Kh[2], z2); z2 = MFMA16(al, Kh[2], z2); z2 = MFMA16(ah, Kl[2], z2);
        z3 = MFMA16(ah, Kh[3], z3); z3 = MFMA16(al, Kh[3], z3); z3 = MFMA16(ah, Kl[3], z3);
        #pragma unroll
        for (int r = 0; r < 4; ++r) {
            float hv = elem(z0[r], z1[r], z2[r], z3[r], cst[r]);
            unsigned short hh, hl;
            split2(hv, hh, hl);
            if (col < 13) {
                outH[(4 * q + r) * 24 + col]       = hh;
                outH[384 + (4 * q + r) * 24 + col] = hl;
            }
        }
    };

    // prefetch x(t) into 8 regs (q<2 lanes; q==1 tail clamped in-bounds)
    auto loadx = [&](int t, float* xv) {
        if (q < 2) {
            const float* p = xrow + t * 13 + 8 * q;
            const int lim = q ? 4 : 7;
            #pragma unroll
            for (int j = 0; j < 8; ++j) {
                int off = j > lim ? lim : j;
                xv[j] = p[off];
            }
        }
    };

    // proj compute from prefetched regs: perm-pack -> 3 MFMA -> relu -> store
    auto projc = [&](const float* xv, unsigned short* oH) {
        bf16x8 axh{}, axl{};
        if (q < 2) {
            unsigned hw0 = packhi2(xv[0], xv[1]);
            unsigned hw1 = packhi2(xv[2], xv[3]);
            unsigned hw2 = packhi2(xv[4], xv[5]);
            unsigned hw3 = packhi2(xv[6], xv[7]);
            unsigned lw0 = packhi2(truncrem(xv[0]), truncrem(xv[1]));
            unsigned lw1 = packhi2(truncrem(xv[2]), truncrem(xv[3]));
            unsigned lw2 = packhi2(truncrem(xv[4]), truncrem(xv[5]));
            unsigned lw3 = packhi2(truncrem(xv[6]), truncrem(xv[7]));
            if (q == 1) {
                hw2 = (hw2 & 0xffffu) | 0x3F800000u;  // elem5 = k=13 -> bf16 1.0 (bias row)
                lw2 &= 0xffffu;
                hw3 = 0u; lw3 = 0u;                   // k=14,15 -> 0
            }
            u32x4 hv = {hw0, hw1, hw2, hw3};
            u32x4 lv = {lw0, lw1, lw2, lw3};
            axh = __builtin_bit_cast(bf16x8, hv);
            axl = __builtin_bit_cast(bf16x8, lv);
        }
        f32x4 zp = {0.f,0.f,0.f,0.f};
        zp = MFMA16(axh, Ph, zp);
        zp = MFMA16(axl, Ph, zp);
        zp = MFMA16(axh, Pl, zp);
        #pragma unroll
        for (int r = 0; r < 4; ++r) {
            float v = fmaxf(zp[r], 0.f);
            unsigned short hh, hl;
            split2(v, hh, hl);
            if (col < 13) {
                oH[(4 * q + r) * 24 + col]       = hh;
                oH[384 + (4 * q + r) * 24 + col] = hl;
            }
        }
    };

    float cst[4] = {0.f, 0.f, 0.f, 0.f};
    float xA0[8], xA1[8], xB0[8], xB1[8];   // x quad-buffer (role 1)

    // prologue: proj(0)->xh[0], proj(1)->xh[1]; load x(2),x(3) into B pair.
    if (role) { loadx(0, xA0); loadx(1, xA1); }
    __syncthreads();             // staging init visible
    if (role) {
        projc(xA0, &xh_s[0][0][0]);
        projc(xA1, &xh_s[1][0][0]);
        loadx(2, xB0); loadx(3, xB1);
    }
    __syncthreads();

    // main loop: 2 super-intervals (4 steps) per iteration, 1 barrier per
    // 2 steps. Slots are compile-time: even interval uses xh/h0 slots {0,1}
    // (reads h0[3] from previous wrap), odd interval uses slots {2,3}.
    for (int s = 0; s < 50; s += 2) {
        // ---- even super-interval s: steps 2s, 2s+1 ----
        if (role == 0) {
            cell(&xh_s[0][0][0], &h0_s[3][0][0], &h0_s[0][0][0], cst);  // cell0(2s)
            cell(&xh_s[1][0][0], &h0_s[0][0][0], &h0_s[1][0][0], cst);  // cell0(2s+1)
        } else {
            if (s < 48) { loadx(2 * s + 4, xA0); loadx(2 * s + 5, xA1); }
            if (s > 0) {
                cell(&h0_s[2][0][0], &h1_s[0][0], &h1_s[0][0], cst);    // cell1(2s-2)
                cell(&h0_s[3][0][0], &h1_s[0][0], &h1_s[0][0], cst);    // cell1(2s-1)
            }
            projc(xB0, &xh_s[2][0][0]);                                 // proj(2s+2)
            projc(xB1, &xh_s[3][0][0]);                                 // proj(2s+3)
        }
        __syncthreads();

        // ---- odd super-interval s+1: steps 2s+2, 2s+3 ----
        if (role == 0) {
            cell(&xh_s[2][0][0], &h0_s[1][0][0], &h0_s[2][0][0], cst);  // cell0(2s+2)
            cell(&xh_s[3][0][0], &h0_s[2][0][0], &h0_s[3][0][0], cst);  // cell0(2s+3)
        } else {
            if (s < 47) { loadx(2 * s + 6, xB0); loadx(2 * s + 7, xB1); }
            cell(&h0_s[0][0][0], &h1_s[0][0], &h1_s[0][0], cst);        // cell1(2s)
            cell(&h0_s[1][0][0], &h1_s[0][0], &h1_s[0][0], cst);        // cell1(2s+1)
            if (s < 48) {
                projc(xA0, &xh_s[0][0][0]);                             // proj(2s+4)
                projc(xA1, &xh_s[1][0][0]);                             // proj(2s+5)
            }
        }
        __syncthreads();
    }

    // ---- final lstm1 steps (t=98, 99) + output projection (role 1 holds
    //      h1; h1_s written/read by this wave only -> no barrier needed) ----
    if (role) {
        cell(&h0_s[2][0][0], &h1_s[0][0], &h1_s[0][0], cst);            // cell1(98)
        cell(&h0_s[3][0][0], &h1_s[0][0], &h1_s[0][0], cst);            // cell1(99)

        bf16x8 Oh{}, Ol{};
        #pragma unroll
        for (int j = 0; j < 8; ++j) {
            int k = 8 * q + j;
            float w = 0.f;
            if (col < 4) {
                if (k < 13)       w = w_out[k * 4 + col];
                else if (k == 13) w = b_out[col];
            }
            unsigned short h_, l_;
            split2(w, h_, l_);
            Oh[j] = bfbits(h_); Ol[j] = bfbits(l_);
        }
        const unsigned short* pA = &h1_s[0][0];
        bf16x8 ah = __builtin_bit_cast(bf16x8, *(const u16x8*)(pA + col * 24 + 8 * qh));
        bf16x8 al = __builtin_bit_cast(bf16x8, *(const u16x8*)(pA + 384 + col * 24 + 8 * qh));
        f32x4 zf = {0.f,0.f,0.f,0.f};
        zf = MFMA16(ah, Oh, zf);
        zf = MFMA16(al, Oh, zf);
        zf = MFMA16(ah, Ol, zf);
        if (col < 4) {
            #pragma unroll
            for (int r = 0; r < 4; ++r)
                out[(size_t)(s0 + 4 * q + r) * 4 + col] = zf[r];
        }
    }
}

extern "C" void kernel_launch(void* const* d_in, const int* in_sizes, int n_in,
                              void* d_out, int out_size, void* d_ws, size_t ws_size,
                              hipStream_t stream) {
    (void)in_sizes; (void)n_in; (void)d_ws; (void)ws_size; (void)out_size;
    lstm_fused<<<dim3(2048), dim3(128), 0, stream>>>(
        (const float*)d_in[0], (const float*)d_in[1], (const float*)d_in[2],
        (const float*)d_in[3], (const float*)d_in[4], (const float*)d_in[5],
        (const float*)d_in[6], (const float*)d_in[7], (const float*)d_in[8],
        (float*)d_out);
}

// Round 8
// 330.328 us; speedup vs baseline: 1.1350x; 1.1350x over previous
//
#include <hip/hip_runtime.h>
#include <cstdint>

typedef __bf16          bf16x8 __attribute__((ext_vector_type(8)));
typedef float           f32x4  __attribute__((ext_vector_type(4)));
typedef float           f32x2  __attribute__((ext_vector_type(2)));
typedef unsigned short  u16x8  __attribute__((ext_vector_type(8)));
typedef unsigned int    u32x4  __attribute__((ext_vector_type(4)));

#define MFMA16(a,b,c) __builtin_amdgcn_mfma_f32_16x16x32_bf16((a),(b),(c),0,0,0)

__device__ __forceinline__ float rcpf(float x) { return __builtin_amdgcn_rcpf(x); }
__device__ __forceinline__ float ex2(float x)  { return __builtin_amdgcn_exp2f(x); }

// truncation hi/lo split: hi = top16(v), lo = trunc16(v - hi).
__device__ __forceinline__ void split2(float v, unsigned short& hi, unsigned short& lo) {
    unsigned u = __builtin_bit_cast(unsigned, v);
    hi = (unsigned short)(u >> 16);
    float rem = v - __builtin_bit_cast(float, u & 0xffff0000u);
    lo = (unsigned short)(__builtin_bit_cast(unsigned, rem) >> 16);
}
__device__ __forceinline__ __bf16 bfbits(unsigned short b) { return __builtin_bit_cast(__bf16, b); }

// one v_perm_b32: result = hi16(b)<<16 | hi16(a)   (pair-pack of truncated bf16)
__device__ __forceinline__ unsigned packhi2(float a, float b) {
    return __builtin_amdgcn_perm(__builtin_bit_cast(unsigned, b),
                                 __builtin_bit_cast(unsigned, a), 0x07060302u);
}
__device__ __forceinline__ float truncrem(float v) {
    return v - __builtin_bit_cast(float, __builtin_bit_cast(unsigned, v) & 0xffff0000u);
}

// ---------------------------------------------------------------------------
// R11 = R9 structure VERBATIM (best: 174 µs; 2 fat waves, 1 barrier/step,
// folded gate scales) + two busy/priority deltas:
//  (1) elem2: elementwise math on float2 ext-vectors -> clang emits VOP3P
//      v_pk_{add,mul,fma}_f32 (2 values/inst). MFMA f32x4 output pairs
//      (r0,r1)/(r2,r3) are already adjacent VGPRs, so no marshalling.
//      IEEE-identical per element -> bit-identical output.
//  (2) role-1 waves run at s_setprio(1): role1 is statically the max-work
//      wave every interval (cell1 + proj + loadx vs cell0); priority
//      compresses the critical wave when both roles are issue-ready.
// Post-mortems locked in: R6/R8 (occupancy/structure), R7 (proj split),
// R10 (barrier-halving adds idle + spills; scheduling levers exhausted).
// Staging images [plane hi/lo][m*24 + k]; pos 13 of every row = 1.0 (hi) so
// weight row k=13 (bias; +FORGET_BIAS on f, then scaled) supplies the bias;
// rows 14/15 zero. h/xh writes col<13-masked to preserve pos 13.
// ---------------------------------------------------------------------------

constexpr float SN1 = -1.4426950408889634f;   // -log2(e)
constexpr float SN2 = -2.8853900817779268f;   // -2 log2(e)
constexpr float C2  =  2.8853900817779268f;   //  2 log2(e)

__global__ __launch_bounds__(128, 4)
void lstm_fused(const float* __restrict__ x,
                const float* __restrict__ w_hidden,
                const float* __restrict__ b_hidden,
                const float* __restrict__ k0,
                const float* __restrict__ b0,
                const float* __restrict__ k1,
                const float* __restrict__ b1,
                const float* __restrict__ w_out,
                const float* __restrict__ b_out,
                float* __restrict__ out)
{
    __shared__ __attribute__((aligned(16))) unsigned short xh_s[2][2][384];
    __shared__ __attribute__((aligned(16))) unsigned short h0_s[2][2][384];
    __shared__ __attribute__((aligned(16))) unsigned short h1_s[2][384];

    const int lane = threadIdx.x & 63;
    const int role = threadIdx.x >> 6;
    const int col  = lane & 15;
    const int q    = lane >> 4;
    const int qh   = q & 1;
    const int s0   = blockIdx.x * 16;

    // ---- init staging: zeros + 1.0 at hi-plane pos 13 of every row ----
    {
        unsigned short* a0 = &xh_s[0][0][0];
        unsigned short* a1 = &h0_s[0][0][0];
        for (int idx = threadIdx.x; idx < 1536; idx += 128) {
            unsigned short v = ((idx % 24) == 13 && ((idx / 384) & 1) == 0)
                             ? (unsigned short)0x3F80 : (unsigned short)0;
            a0[idx] = v; a1[idx] = v;
        }
        unsigned short* a2 = &h1_s[0][0];
        for (int idx = threadIdx.x; idx < 768; idx += 128) {
            unsigned short v = ((idx % 24) == 13 && ((idx / 384) & 1) == 0)
                             ? (unsigned short)0x3F80 : (unsigned short)0;
            a2[idx] = v;
        }
    }

    // ---- role-selected LSTM weights as B-fragments (hi/lo), bias row k=13;
    //      gate pre-scales folded in: g==1 (j) -> SN2, else SN1 ----
    const float* kp = role ? k1 : k0;
    const float* bb = role ? b1 : b0;
    bf16x8 Kh[4], Kl[4];
    #pragma unroll
    for (int g = 0; g < 4; ++g) {
        const float sg = (g == 1) ? SN2 : SN1;
        bf16x8 hv{}, lv{};
        #pragma unroll
        for (int j = 0; j < 8; ++j) {
            int k = 8 * q + j;
            float w = 0.f;
            if (col < 13) {
                if (k < 13)                 w = kp[k * 52 + 13 * g + col];
                else if (k == 13)           w = bb[13 * g + col] + (g == 2 ? 1.f : 0.f); // +FORGET_BIAS on f
                else if (k >= 16 && k < 29) w = kp[(13 + k - 16) * 52 + 13 * g + col];
            }
            w *= sg;
            unsigned short h_, l_;
            split2(w, h_, l_);
            hv[j] = bfbits(h_); lv[j] = bfbits(l_);
        }
        Kh[g] = hv; Kl[g] = lv;
    }

    // ---- proj weights (role 1 only; UNscaled — relu stays explicit) ----
    bf16x8 Ph{}, Pl{};
    if (role) {
        #pragma unroll
        for (int j = 0; j < 8; ++j) {
            int k = 8 * q + j;
            float w = 0.f;
            if (col < 13) {
                if (k < 13)       w = w_hidden[k * 13 + col];
                else if (k == 13) w = b_hidden[col];
            }
            unsigned short h_, l_;
            split2(w, h_, l_);
            Ph[j] = bfbits(h_); Pl[j] = bfbits(l_);
        }
    }

    const float* xrow = x + (size_t)(s0 + col) * 1300;

    // role1 = the statically max-work wave every interval -> issue priority
    if (role) __builtin_amdgcn_s_setprio(1);

    const f32x2 v1  = {1.f, 1.f};
    const f32x2 vC2 = {C2, C2};
    const f32x2 vmC2 = {-C2, -C2};

    // packed-pair elem: inputs pre-scaled (-KL*z; j: -2KL*z); cs = -2KL*c.
    // All add/mul/fma on f32x2 -> VOP3P; trans stays scalar (no pk trans).
    auto elem2 = [&](f32x2 zi, f32x2 zj, f32x2 zf, f32x2 zo, f32x2& cs) -> f32x2 {
        f32x2 a  = {ex2(zi.x), ex2(zi.y)};
        f32x2 b  = {ex2(zj.x), ex2(zj.y)};
        f32x2 fe = {ex2(zf.x), ex2(zf.y)};
        f32x2 g  = {ex2(zo.x), ex2(zo.y)};
        f32x2 opa = v1 + a, opb = v1 + b, opf = v1 + fe;
        f32x2 pab = opa * opb;
        f32x2 pq  = pab * opf;
        f32x2 r1  = {rcpf(pq.x), rcpf(pq.y)};
        f32x2 tt  = __builtin_elementwise_fma(b, vC2, vmC2);      // -2KL*(1-b)
        f32x2 cn  = __builtin_elementwise_fma(cs, pab, tt * opf) * r1;
        cs = cn;
        f32x2 d   = {ex2(cn.x), ex2(cn.y)};
        f32x2 pr  = (v1 + d) * (v1 + g);
        f32x2 r2  = {rcpf(pr.x), rcpf(pr.y)};
        return (v1 - d) * r2;                                     // tanh(c)*sig(o)
    };

    auto cell = [&](const unsigned short* inH, const unsigned short* hidH,
                    unsigned short* outH, f32x2* cst) {
        const unsigned short* pA = (q < 2) ? inH : hidH;
        bf16x8 ah = __builtin_bit_cast(bf16x8, *(const u16x8*)(pA + col * 24 + 8 * qh));
        bf16x8 al = __builtin_bit_cast(bf16x8, *(const u16x8*)(pA + 384 + col * 24 + 8 * qh));
        f32x4 z0 = {0.f,0.f,0.f,0.f}, z1 = z0, z2 = z0, z3 = z0;
        z0 = MFMA16(ah, Kh[0], z0); z0 = MFMA16(al, Kh[0], z0); z0 = MFMA16(ah, Kl[0], z0);
        z1 = MFMA16(ah, Kh[1], z1); z1 = MFMA16(al, Kh[1], z1); z1 = MFMA16(ah, Kl[1], z1);
        z2 = MFMA16(ah, Kh[2], z2); z2 = MFMA16(al, Kh[2], z2); z2 = MFMA16(ah, Kl[2], z2);
        z3 = MFMA16(ah, Kh[3], z3); z3 = MFMA16(al, Kh[3], z3); z3 = MFMA16(ah, Kl[3], z3);
        #pragma unroll
        for (int pr = 0; pr < 2; ++pr) {
            f32x2 zi = pr ? __builtin_shufflevector(z0, z0, 2, 3)
                          : __builtin_shufflevector(z0, z0, 0, 1);
            f32x2 zj = pr ? __builtin_shufflevector(z1, z1, 2, 3)
                          : __builtin_shufflevector(z1, z1, 0, 1);
            f32x2 zf = pr ? __builtin_shufflevector(z2, z2, 2, 3)
                          : __builtin_shufflevector(z2, z2, 0, 1);
            f32x2 zo = pr ? __builtin_shufflevector(z3, z3, 2, 3)
                          : __builtin_shufflevector(z3, z3, 0, 1);
            f32x2 hv = elem2(zi, zj, zf, zo, cst[pr]);
            unsigned short hh0, hl0, hh1, hl1;
            split2(hv.x, hh0, hl0);
            split2(hv.y, hh1, hl1);
            if (col < 13) {
                int r0 = 2 * pr;
                outH[(4 * q + r0) * 24 + col]           = hh0;
                outH[384 + (4 * q + r0) * 24 + col]     = hl0;
                outH[(4 * q + r0 + 1) * 24 + col]       = hh1;
                outH[384 + (4 * q + r0 + 1) * 24 + col] = hl1;
            }
        }
    };

    // prefetch x(t) into 8 regs (q<2 lanes; q==1 tail clamped in-bounds)
    auto loadx = [&](int t, float* xv) {
        if (q < 2) {
            const float* p = xrow + t * 13 + 8 * q;
            const int lim = q ? 4 : 7;
            #pragma unroll
            for (int j = 0; j < 8; ++j) {
                int off = j > lim ? lim : j;
                xv[j] = p[off];
            }
        }
    };

    // proj compute from prefetched regs: perm-pack -> 3 MFMA -> relu -> store
    auto projc = [&](const float* xv, unsigned short* oH) {
        bf16x8 axh{}, axl{};
        if (q < 2) {
            unsigned hw0 = packhi2(xv[0], xv[1]);
            unsigned hw1 = packhi2(xv[2], xv[3]);
            unsigned hw2 = packhi2(xv[4], xv[5]);
            unsigned hw3 = packhi2(xv[6], xv[7]);
            unsigned lw0 = packhi2(truncrem(xv[0]), truncrem(xv[1]));
            unsigned lw1 = packhi2(truncrem(xv[2]), truncrem(xv[3]));
            unsigned lw2 = packhi2(truncrem(xv[4]), truncrem(xv[5]));
            unsigned lw3 = packhi2(truncrem(xv[6]), truncrem(xv[7]));
            if (q == 1) {
                hw2 = (hw2 & 0xffffu) | 0x3F800000u;  // elem5 = k=13 -> bf16 1.0 (bias row)
                lw2 &= 0xffffu;
                hw3 = 0u; lw3 = 0u;                   // k=14,15 -> 0
            }
            u32x4 hv = {hw0, hw1, hw2, hw3};
            u32x4 lv = {lw0, lw1, lw2, lw3};
            axh = __builtin_bit_cast(bf16x8, hv);
            axl = __builtin_bit_cast(bf16x8, lv);
        }
        f32x4 zp = {0.f,0.f,0.f,0.f};
        zp = MFMA16(axh, Ph, zp);
        zp = MFMA16(axl, Ph, zp);
        zp = MFMA16(axh, Pl, zp);
        #pragma unroll
        for (int r = 0; r < 4; ++r) {
            float v = fmaxf(zp[r], 0.f);
            unsigned short hh, hl;
            split2(v, hh, hl);
            if (col < 13) {
                oH[(4 * q + r) * 24 + col]       = hh;
                oH[384 + (4 * q + r) * 24 + col] = hl;
            }
        }
    };

    f32x2 cst[2] = {{0.f, 0.f}, {0.f, 0.f}};
    float xA[8], xB[8];          // x register double-buffer (role 1)

    if (role) loadx(0, xA);
    __syncthreads();             // staging init visible
    if (role) { projc(xA, &xh_s[0][0][0]); loadx(1, xB); }
    __syncthreads();

    // unrolled-by-2 main loop: p is compile-time in each body.
    // even step i:  role1 prefetches x(i+2)->xA, cell1(i-1), proj(i+1) from xB.
    // odd  step i+1: role1 prefetches x(i+3)->xB, cell1(i), proj(i+2) from xA.
    for (int i = 0; i < 100; i += 2) {
        if (role == 0) {
            cell(&xh_s[0][0][0], &h0_s[1][0][0], &h0_s[0][0][0], cst);
        } else {
            if (i < 98) loadx(i + 2, xA);
            if (i > 0)  cell(&h0_s[1][0][0], &h1_s[0][0], &h1_s[0][0], cst);
            projc(xB, &xh_s[1][0][0]);                 // proj(i+1), t<=99
        }
        __syncthreads();
        if (role == 0) {
            cell(&xh_s[1][0][0], &h0_s[0][0][0], &h0_s[1][0][0], cst);
        } else {
            if (i < 97) loadx(i + 3, xB);
            cell(&h0_s[0][0][0], &h1_s[0][0], &h1_s[0][0], cst);
            if (i < 98) projc(xA, &xh_s[0][0][0]);     // proj(i+2)
        }
        __syncthreads();
    }

    // ---- final lstm1 step (t=99) + output projection (role 1 holds h1;
    //      h1_s written/read by this wave only -> no barrier needed) ----
    if (role) {
        cell(&h0_s[1][0][0], &h1_s[0][0], &h1_s[0][0], cst);

        bf16x8 Oh{}, Ol{};
        #pragma unroll
        for (int j = 0; j < 8; ++j) {
            int k = 8 * q + j;
            float w = 0.f;
            if (col < 4) {
                if (k < 13)       w = w_out[k * 4 + col];
                else if (k == 13) w = b_out[col];
            }
            unsigned short h_, l_;
            split2(w, h_, l_);
            Oh[j] = bfbits(h_); Ol[j] = bfbits(l_);
        }
        const unsigned short* pA = &h1_s[0][0];
        bf16x8 ah = __builtin_bit_cast(bf16x8, *(const u16x8*)(pA + col * 24 + 8 * qh));
        bf16x8 al = __builtin_bit_cast(bf16x8, *(const u16x8*)(pA + 384 + col * 24 + 8 * qh));
        f32x4 zf = {0.f,0.f,0.f,0.f};
        zf = MFMA16(ah, Oh, zf);
        zf = MFMA16(al, Oh, zf);
        zf = MFMA16(ah, Ol, zf);
        if (col < 4) {
            #pragma unroll
            for (int r = 0; r < 4; ++r)
                out[(size_t)(s0 + 4 * q + r) * 4 + col] = zf[r];
        }
    }
}

extern "C" void kernel_launch(void* const* d_in, const int* in_sizes, int n_in,
                              void* d_out, int out_size, void* d_ws, size_t ws_size,
                              hipStream_t stream) {
    (void)in_sizes; (void)n_in; (void)d_ws; (void)ws_size; (void)out_size;
    lstm_fused<<<dim3(2048), dim3(128), 0, stream>>>(
        (const float*)d_in[0], (const float*)d_in[1], (const float*)d_in[2],
        (const float*)d_in[3], (const float*)d_in[4], (const float*)d_in[5],
        (const float*)d_in[6], (const float*)d_in[7], (const float*)d_in[8],
        (float*)d_out);
}